// Round 1
// baseline (468.247 us; speedup 1.0000x reference)
//
#include <hip/hip_runtime.h>
#include <hip/hip_bf16.h>
#include <math.h>

#define MB 512
#define T 256
#define NP1 201
#define D 4
#define KNN 5

// ws layout:
//   used : float[MB*T]              @ 0          (512 KB)
//   vis  : u64  [MB*T*4]            @ 524288     (4 MB)
//   pack : float[MB*NP1*12]         @ 4718592    (~4.94 MB)
// total ~9.2 MB

// ---------------------------------------------------------------------------
// Kernel 1: per-batch sequential scan. One thread per batch b.
// Emits PRE-step state at each t: used[t], vis[t] (201-bit mask in 4 u64).
// Also zero-inits the entropy output (d_out is poisoned 0xAA by harness).
// Accumulation is pure sequential f32 adds -> bit-exact vs f32 reference scan.
// ---------------------------------------------------------------------------
__global__ void scan_kernel(const float* __restrict__ demands,
                            const int* __restrict__ actions,
                            float* __restrict__ used_out,
                            unsigned long long* __restrict__ vis_out,
                            float* __restrict__ ent_out) {
    int b = blockIdx.x * blockDim.x + threadIdx.x;
    if (b >= MB) return;
    ent_out[b] = 0.f;
    unsigned long long v0 = 0, v1 = 0, v2 = 0, v3 = 0;
    float used = 0.f;
    const int* act_b = actions + b * T;
    const float* dem_b = demands + b * NP1;
    for (int t = 0; t < T; ++t) {
        used_out[b * T + t] = used;
        unsigned long long* vp = vis_out + (size_t)(b * T + t) * 4;
        vp[0] = v0; vp[1] = v1; vp[2] = v2; vp[3] = v3;
        int a = act_b[t];
        float dem = dem_b[a];
        used = (a == 0) ? 0.f : (used + dem);
        if (a < 64)        v0 |= 1ull << a;
        else if (a < 128)  v1 |= 1ull << (a - 64);
        else if (a < 192)  v2 |= 1ull << (a - 128);
        else               v3 |= 1ull << (a - 192);
        v0 &= ~1ull;  // depot bit always cleared (matches .at[:,0].set(False))
    }
}

// ---------------------------------------------------------------------------
// Kernel 2: per-(b,n) t-invariant precompute.
//   z[c]   = sum_d Wq_w[d,c] * psi[b,n,d]          (c = 0..7)
//   const  = Wq_b . psi  +  lam*interference  +  nu*dem/cap
// Packed as 12 floats: z0..z7, const, x, y, dem.
// ---------------------------------------------------------------------------
__global__ void pre_kernel(const float* __restrict__ psi,
                           const float* __restrict__ demands,
                           const float* __restrict__ coords,
                           const float* __restrict__ Wq_w,
                           const float* __restrict__ Wq_b,
                           const float* __restrict__ lam_p,
                           const float* __restrict__ nu_p,
                           const int* __restrict__ cap_p,
                           const int* __restrict__ knn,
                           float* __restrict__ pack) {
    int i = blockIdx.x * blockDim.x + threadIdx.x;
    if (i >= MB * NP1) return;
    int b = i / NP1;
    float lam = fminf(fmaxf(lam_p[0], -2.f), 3.f);
    float nu  = fminf(fmaxf(nu_p[0],  -2.f), 3.f);
    float cap = fmaxf((float)cap_p[0], 1e-8f);

    float4 pn = *(const float4*)(psi + (size_t)i * 4);

    float z[8];
#pragma unroll
    for (int c = 0; c < 8; ++c)
        z[c] = pn.x * Wq_w[0 * 8 + c] + pn.y * Wq_w[1 * 8 + c]
             + pn.z * Wq_w[2 * 8 + c] + pn.w * Wq_w[3 * 8 + c];

    float interf = 0.f;
    const int* kn = knn + (size_t)i * KNN;
#pragma unroll
    for (int k = 0; k < KNN; ++k) {
        int j = kn[k];
        float4 pj = *(const float4*)(psi + ((size_t)b * NP1 + j) * 4);
        interf += pn.x * pj.x + pn.y * pj.y + pn.z * pj.z + pn.w * pj.w;
    }

    float dem = demands[i];
    float cst = Wq_b[0] * pn.x + Wq_b[1] * pn.y + Wq_b[2] * pn.z + Wq_b[3] * pn.w
              + lam * interf + nu * (dem / cap);
    float x = coords[(size_t)i * 2];
    float y = coords[(size_t)i * 2 + 1];

    float* o = pack + (size_t)i * 12;
    float4 o0 = {z[0], z[1], z[2], z[3]};
    float4 o1 = {z[4], z[5], z[6], z[7]};
    float4 o2 = {cst, x, y, dem};
    *(float4*)(o)     = o0;
    *(float4*)(o + 4) = o1;
    *(float4*)(o + 8) = o2;
}

// ---------------------------------------------------------------------------
// Kernel 3: one wave per (b,t) row. 4 n-slots per lane (n = lane + 64*j).
// Wave-only reductions: ballot (has_cust), shfl-xor max, shfl-xor (S,W) pair.
//   lp[b,t]    = score[act] - m - log(S)
//   entropy[b] += (log(S) - W/S) / T    (atomicAdd, zeroed by scan_kernel)
// ---------------------------------------------------------------------------
__global__ __launch_bounds__(256) void score_kernel(
        const float* __restrict__ psi,
        const float* __restrict__ coords,
        const int* __restrict__ actions,
        const float* __restrict__ used_ws,
        const unsigned long long* __restrict__ vis_ws,
        const float* __restrict__ pack,
        const float* __restrict__ mu_p,
        const int* __restrict__ cap_p,
        float* __restrict__ lp_out,
        float* __restrict__ ent_out) {
    int wave = threadIdx.x >> 6;
    int lane = threadIdx.x & 63;
    int row  = blockIdx.x * 4 + wave;   // row = b*T + t
    int b = row >> 8;
    int t = row & 255;

    float mu  = fminf(fmaxf(mu_p[0], 0.f), 20.f);
    float cap = fmaxf((float)cap_p[0], 1e-8f);

    int cur = (t == 0) ? 0 : actions[b * T + t - 1];
    int act = actions[b * T + t];
    float used = used_ws[row];
    float remaining = cap - used;
    float cap_norm = remaining / cap;

    const unsigned long long* vp = vis_ws + (size_t)row * 4;
    unsigned long long w0 = vp[0], w1 = vp[1], w2 = vp[2], w3 = vp[3];

    bool at_depot = (cur == 0);
    float4 psic;
    if (at_depot) { psic.x = 0.f; psic.y = 0.f; psic.z = 0.f; psic.w = 0.f; }
    else          { psic = *(const float4*)(psi + ((size_t)b * NP1 + cur) * 4); }
    float xc = coords[((size_t)b * NP1 + cur) * 2];
    float yc = coords[((size_t)b * NP1 + cur) * 2 + 1];
    float tnorm = (float)t / 200.f;

    float sc[4];
    bool avail_any = false;
#pragma unroll
    for (int j = 0; j < 4; ++j) {
        int n = lane + 64 * j;
        float s = -1e9f;
        if (n < NP1) {
            const float* pk = pack + ((size_t)b * NP1 + n) * 12;
            float4 z0 = *(const float4*)pk;
            float4 z1 = *(const float4*)(pk + 4);
            float4 z2 = *(const float4*)(pk + 8);
            float sco = z2.x
                      + psic.x * z0.x + psic.y * z0.y + psic.z * z0.z + psic.w * z0.w
                      + cap_norm * z1.x + tnorm * z1.y + xc * z1.z + yc * z1.w;
            float dx = z2.y - xc, dy = z2.z - yc;
            sco -= mu * sqrtf(dx * dx + dy * dy + 1e-12f);
            unsigned long long wj = (j == 0) ? w0 : (j == 1) ? w1 : (j == 2) ? w2 : w3;
            bool visn = (wj >> lane) & 1;
            if (n == 0) {
                s = sco;                       // depot: resolved after ballot
            } else {
                bool maskn = visn || (z2.w > remaining);
                if (!maskn) avail_any = true;
                s = maskn ? -1e9f : sco;
            }
        }
        sc[j] = s;
    }

    unsigned long long bal = __ballot(avail_any);
    bool has_cust = (bal != 0ull);
    if (lane == 0 && at_depot && has_cust) sc[0] = -1e9f;

    // wave max
    float m = fmaxf(fmaxf(sc[0], sc[1]), fmaxf(sc[2], sc[3]));
#pragma unroll
    for (int off = 32; off > 0; off >>= 1) m = fmaxf(m, __shfl_xor(m, off));

    // fused sum-exp and sum e*(s-m)
    float S = 0.f, W = 0.f;
#pragma unroll
    for (int j = 0; j < 4; ++j) {
        float d = sc[j] - m;
        float ex = __expf(d);
        S += ex;
        W += ex * d;
    }
#pragma unroll
    for (int off = 32; off > 0; off >>= 1) {
        S += __shfl_xor(S, off);
        W += __shfl_xor(W, off);
    }
    float L = logf(S);

    if (lane == (act & 63)) {
        int jact = act >> 6;
        float sa = (jact == 0) ? sc[0] : (jact == 1) ? sc[1] : (jact == 2) ? sc[2] : sc[3];
        lp_out[row] = sa - m - L;
    }
    if (lane == 0) {
        atomicAdd(&ent_out[b], (L - W / S) * (1.f / (float)T));
    }
}

extern "C" void kernel_launch(void* const* d_in, const int* in_sizes, int n_in,
                              void* d_out, int out_size, void* d_ws, size_t ws_size,
                              hipStream_t stream) {
    const float* demands = (const float*)d_in[0];
    const float* coords  = (const float*)d_in[1];
    const float* psi     = (const float*)d_in[2];
    const float* Wq_w    = (const float*)d_in[3];
    const float* Wq_b    = (const float*)d_in[4];
    const float* lam_p   = (const float*)d_in[5];
    const float* mu_p    = (const float*)d_in[6];
    const float* nu_p    = (const float*)d_in[7];
    const int*   actions = (const int*)d_in[8];
    const int*   knn     = (const int*)d_in[9];
    const int*   cap_p   = (const int*)d_in[10];

    float* lp_out  = (float*)d_out;
    float* ent_out = lp_out + MB * T;

    char* ws = (char*)d_ws;
    float* used_ws = (float*)ws;                                        // 512 KB
    unsigned long long* vis_ws = (unsigned long long*)(ws + 524288);    // 4 MB
    float* pack = (float*)(ws + 524288 + 4194304);                      // ~4.94 MB

    scan_kernel<<<8, 64, 0, stream>>>(demands, actions, used_ws, vis_ws, ent_out);
    pre_kernel<<<(MB * NP1 + 255) / 256, 256, 0, stream>>>(
        psi, demands, coords, Wq_w, Wq_b, lam_p, nu_p, cap_p, knn, pack);
    score_kernel<<<(MB * T) / 4, 256, 0, stream>>>(
        psi, coords, actions, used_ws, vis_ws, pack, mu_p, cap_p, lp_out, ent_out);
}

// Round 3
// 142.284 us; speedup vs baseline: 3.2909x; 3.2909x over previous
//
#include <hip/hip_runtime.h>
#include <hip/hip_bf16.h>
#include <math.h>

#define MB 512
#define T 256
#define NP1 201
#define KNN 5

// One block per batch b (512 blocks x 256 threads). Thread t owns row (b,t).
// LDS (~25.6 KB): staged inputs, z-pack (SoA float4), visited bitmask scan.
__global__ __launch_bounds__(256) void fused_kernel(
        const float* __restrict__ demands,
        const float* __restrict__ coords,
        const float* __restrict__ psi,
        const float* __restrict__ Wq_w,
        const float* __restrict__ Wq_b,
        const float* __restrict__ lam_p,
        const float* __restrict__ mu_p,
        const float* __restrict__ nu_p,
        const int* __restrict__ actions,
        const int* __restrict__ knn,
        const int* __restrict__ cap_p,
        float* __restrict__ lp_out,
        float* __restrict__ ent_out) {
    __shared__ int   actL[T];
    __shared__ float demActL[T];
    __shared__ float usedL[T];
    __shared__ unsigned long long visW[4][T];   // SoA: word-major, coalesced in t
    __shared__ float4 zA[NP1];   // z0..z3   (psi_cur weights)
    __shared__ float4 zB[NP1];   // z4..z7   (cap_norm, t_norm, xc, yc weights)
    __shared__ float4 zC[NP1];   // const, x_n, y_n, dem_n
    __shared__ float4 psiL[NP1];
    __shared__ float2 coordL[NP1];
    __shared__ float  entPart[4];

    const int b = blockIdx.x;
    const int t = threadIdx.x;

    const float lam = fminf(fmaxf(lam_p[0], -2.f), 3.f);
    const float nu  = fminf(fmaxf(nu_p[0],  -2.f), 3.f);
    const float mu  = fminf(fmaxf(mu_p[0],   0.f), 20.f);
    const float cap = fmaxf((float)cap_p[0], 1e-8f);

    // ---- prologue: gather per-t action/demand, init point visited masks ----
    const int a_t = actions[b * T + t];
    actL[t] = a_t;
    demActL[t] = demands[b * NP1 + a_t];
    visW[0][t] = (a_t < 64)              ? (1ull << a_t)         : 0ull;
    visW[1][t] = (a_t >= 64 && a_t < 128)  ? (1ull << (a_t - 64))  : 0ull;
    visW[2][t] = (a_t >= 128 && a_t < 192) ? (1ull << (a_t - 128)) : 0ull;
    visW[3][t] = (a_t >= 192)            ? (1ull << (a_t - 192)) : 0ull;

    // ---- prologue: per-node pack (t-invariant) for n = t < 201 ----
    if (t < NP1) {
        const int n = t;
        const float4 pn = *(const float4*)(psi + ((size_t)b * NP1 + n) * 4);
        psiL[n] = pn;
        const float2 cc2 = *(const float2*)(coords + ((size_t)b * NP1 + n) * 2);
        coordL[n] = cc2;
        float z[8];
#pragma unroll
        for (int c = 0; c < 8; ++c)
            z[c] = pn.x * Wq_w[c] + pn.y * Wq_w[8 + c]
                 + pn.z * Wq_w[16 + c] + pn.w * Wq_w[24 + c];
        float interf = 0.f;
        const int* kn = knn + ((size_t)b * NP1 + n) * KNN;
#pragma unroll
        for (int k = 0; k < KNN; ++k) {
            const int j = kn[k];
            const float4 pj = *(const float4*)(psi + ((size_t)b * NP1 + j) * 4);
            interf += pn.x * pj.x + pn.y * pj.y + pn.z * pj.z + pn.w * pj.w;
        }
        const float dem = demands[b * NP1 + n];
        const float cst = Wq_b[0] * pn.x + Wq_b[1] * pn.y + Wq_b[2] * pn.z + Wq_b[3] * pn.w
                        + lam * interf + nu * (dem / cap);
        float4 va = {z[0], z[1], z[2], z[3]};
        float4 vb = {z[4], z[5], z[6], z[7]};
        float4 vc = {cst, cc2.x, cc2.y, dem};
        zA[n] = va; zB[n] = vb; zC[n] = vc;
    }
    __syncthreads();

    // ---- inclusive prefix-OR scan of visited masks (bitwise => exact) ----
#pragma unroll
    for (int off = 1; off < T; off <<= 1) {
        unsigned long long x0, x1, x2, x3;
        const bool doit = (t >= off);
        if (doit) { x0 = visW[0][t - off]; x1 = visW[1][t - off];
                    x2 = visW[2][t - off]; x3 = visW[3][t - off]; }
        __syncthreads();
        if (doit) { visW[0][t] |= x0; visW[1][t] |= x1;
                    visW[2][t] |= x2; visW[3][t] |= x3; }
        __syncthreads();
    }

    // ---- serial f32 'used' scan (bit-exact sequential order) ----
    if (t == 0) {
        float used = 0.f;
        for (int i = 0; i < T; ++i) {
            usedL[i] = used;
            const int a = actL[i];
            used = (a == 0) ? 0.f : (used + demActL[i]);
        }
    }
    __syncthreads();

    // ---- per-thread row state ----
    const int cur = (t == 0) ? 0 : actL[t - 1];
    unsigned long long v0 = 0, v1 = 0, v2 = 0, v3 = 0;
    if (t > 0) {
        v0 = visW[0][t - 1] & ~1ull;   // depot bit always cleared
        v1 = visW[1][t - 1];
        v2 = visW[2][t - 1];
        v3 = visW[3][t - 1];
    }
    const float used = usedL[t];
    const float rem  = cap - used;
    const float capn = rem / cap;
    const bool  at_depot = (cur == 0);
    float4 pc;
    if (at_depot) { pc.x = 0.f; pc.y = 0.f; pc.z = 0.f; pc.w = 0.f; }
    else          { pc = psiL[cur]; }
    const float2 cc = coordL[cur];
    const float tn = (float)t / 200.f;

    // ---- online softmax + entropy over n, LDS broadcast reads ----
    float m = -1e30f, S = 0.f, W = 0.f, sAct = 0.f;
    bool hasCust = false;

#define BODY(nn, ww)                                                          \
    {                                                                         \
        const int q = (nn);                                                   \
        const float4 a4 = zA[q];                                              \
        const float4 b4 = zB[q];                                              \
        const float4 c4 = zC[q];                                              \
        float sco = c4.x                                                      \
                  + pc.x * a4.x + pc.y * a4.y + pc.z * a4.z + pc.w * a4.w     \
                  + capn * b4.x + tn * b4.y + cc.x * b4.z + cc.y * b4.w;      \
        const float dx = c4.y - cc.x, dy = c4.z - cc.y;                       \
        sco -= mu * sqrtf(dx * dx + dy * dy + 1e-12f);                        \
        const bool visn = (ww >> (q & 63)) & 1;                               \
        const bool maskn = visn || (c4.w > rem);                              \
        hasCust = hasCust || !maskn;                                          \
        const float s = maskn ? -1e9f : sco;                                  \
        const float mN = fmaxf(m, s);                                         \
        const float al = __expf(m - mN);                                      \
        const float d  = __expf(s - mN);                                      \
        W = (W + S * (m - mN)) * al + d * (s - mN);                           \
        S = S * al + d;                                                       \
        m = mN;                                                               \
        sAct = (q == a_t) ? s : sAct;                                         \
    }

#pragma unroll 4
    for (int n = 1; n < 64; ++n) BODY(n, v0)
#pragma unroll 4
    for (int n = 64; n < 128; ++n) BODY(n, v1)
#pragma unroll 4
    for (int n = 128; n < 192; ++n) BODY(n, v2)
#pragma unroll 4
    for (int n = 192; n < 201; ++n) BODY(n, v3)

    // ---- depot (n = 0): mask = at_depot & has_customer ----
    {
        const float4 a4 = zA[0];
        const float4 b4 = zB[0];
        const float4 c4 = zC[0];
        float sco = c4.x
                  + pc.x * a4.x + pc.y * a4.y + pc.z * a4.z + pc.w * a4.w
                  + capn * b4.x + tn * b4.y + cc.x * b4.z + cc.y * b4.w;
        const float dx = c4.y - cc.x, dy = c4.z - cc.y;
        sco -= mu * sqrtf(dx * dx + dy * dy + 1e-12f);
        const float s0 = (at_depot && hasCust) ? -1e9f : sco;
        const float mN = fmaxf(m, s0);
        const float al = __expf(m - mN);
        const float d  = __expf(s0 - mN);
        W = (W + S * (m - mN)) * al + d * (s0 - mN);
        S = S * al + d;
        m = mN;
        sAct = (a_t == 0) ? s0 : sAct;
    }

    const float L = logf(S);
    lp_out[b * T + t] = sAct - m - L;

    // ---- entropy: block reduction, one write per b ----
    float ent = L - W / S;
#pragma unroll
    for (int off = 32; off > 0; off >>= 1) ent += __shfl_xor(ent, off);
    if ((t & 63) == 0) entPart[t >> 6] = ent;
    __syncthreads();
    if (t == 0)
        ent_out[b] = (entPart[0] + entPart[1] + entPart[2] + entPart[3]) * (1.f / (float)T);
}

extern "C" void kernel_launch(void* const* d_in, const int* in_sizes, int n_in,
                              void* d_out, int out_size, void* d_ws, size_t ws_size,
                              hipStream_t stream) {
    const float* demands = (const float*)d_in[0];
    const float* coords  = (const float*)d_in[1];
    const float* psi     = (const float*)d_in[2];
    const float* Wq_w    = (const float*)d_in[3];
    const float* Wq_b    = (const float*)d_in[4];
    const float* lam_p   = (const float*)d_in[5];
    const float* mu_p    = (const float*)d_in[6];
    const float* nu_p    = (const float*)d_in[7];
    const int*   actions = (const int*)d_in[8];
    const int*   knn     = (const int*)d_in[9];
    const int*   cap_p   = (const int*)d_in[10];

    float* lp_out  = (float*)d_out;
    float* ent_out = lp_out + MB * T;

    fused_kernel<<<MB, T, 0, stream>>>(demands, coords, psi, Wq_w, Wq_b,
                                       lam_p, mu_p, nu_p, actions, knn, cap_p,
                                       lp_out, ent_out);
}

// Round 4
// 132.184 us; speedup vs baseline: 3.5424x; 1.0764x over previous
//
#include <hip/hip_runtime.h>
#include <hip/hip_bf16.h>
#include <math.h>

#define MB 512
#define T 256
#define NP1 201
#define KNN 5

// One block per batch b (512 blocks x 256 threads). Thread t owns row (b,t).
// Hot loop: 2 LDS broadcast b128 reads + ~28 VALU per n, 4 independent
// online-softmax streams for ILP.
__global__ __launch_bounds__(256) void fused_kernel(
        const float* __restrict__ demands,
        const float* __restrict__ coords,
        const float* __restrict__ psi,
        const float* __restrict__ Wq_w,
        const float* __restrict__ Wq_b,
        const float* __restrict__ lam_p,
        const float* __restrict__ mu_p,
        const float* __restrict__ nu_p,
        const int* __restrict__ actions,
        const int* __restrict__ knn,
        const int* __restrict__ cap_p,
        float* __restrict__ lp_out,
        float* __restrict__ ent_out) {
    __shared__ int   actL[T];
    __shared__ float demActL[T];
    __shared__ float usedL[T];
    __shared__ unsigned long long visW[4][T];
    __shared__ float4 psiL[NP1];   // psi_n
    __shared__ float4 zC[NP1];     // const_n, x_n, y_n, dem_n
    __shared__ float  entPart[4];

    const int b = blockIdx.x;
    const int t = threadIdx.x;

    const float lam = fminf(fmaxf(lam_p[0], -2.f), 3.f);
    const float nu  = fminf(fmaxf(nu_p[0],  -2.f), 3.f);
    const float mu  = fminf(fmaxf(mu_p[0],   0.f), 20.f);
    const float cap = fmaxf((float)cap_p[0], 1e-8f);

    // ---- prologue: per-t action/demand + point visited masks ----
    const int a_t = actions[b * T + t];
    actL[t] = a_t;
    demActL[t] = demands[b * NP1 + a_t];
    visW[0][t] = (a_t < 64)                ? (1ull << a_t)         : 0ull;
    visW[1][t] = (a_t >= 64 && a_t < 128)  ? (1ull << (a_t - 64))  : 0ull;
    visW[2][t] = (a_t >= 128 && a_t < 192) ? (1ull << (a_t - 128)) : 0ull;
    visW[3][t] = (a_t >= 192)              ? (1ull << (a_t - 192)) : 0ull;

    // ---- prologue: per-node pack (t-invariant), n = t < 201 ----
    if (t < NP1) {
        const int n = t;
        const float4 pn = *(const float4*)(psi + ((size_t)b * NP1 + n) * 4);
        psiL[n] = pn;
        const float2 cc2 = *(const float2*)(coords + ((size_t)b * NP1 + n) * 2);
        float interf = 0.f;
        const int* kn = knn + ((size_t)b * NP1 + n) * KNN;
#pragma unroll
        for (int k = 0; k < KNN; ++k) {
            const int j = kn[k];
            const float4 pj = *(const float4*)(psi + ((size_t)b * NP1 + j) * 4);
            interf += pn.x * pj.x + pn.y * pj.y + pn.z * pj.z + pn.w * pj.w;
        }
        const float dem = demands[b * NP1 + n];
        const float cst = lam * interf + nu * (dem / cap);
        float4 vc = {cst, cc2.x, cc2.y, dem};
        zC[n] = vc;
    }
    __syncthreads();

    // ---- inclusive prefix-OR scan of visited masks (bitwise => exact) ----
#pragma unroll
    for (int off = 1; off < T; off <<= 1) {
        unsigned long long x0, x1, x2, x3;
        const bool doit = (t >= off);
        if (doit) { x0 = visW[0][t - off]; x1 = visW[1][t - off];
                    x2 = visW[2][t - off]; x3 = visW[3][t - off]; }
        __syncthreads();
        if (doit) { visW[0][t] |= x0; visW[1][t] |= x1;
                    visW[2][t] |= x2; visW[3][t] |= x3; }
        __syncthreads();
    }

    // ---- serial f32 'used' scan (bit-exact sequential order) ----
    if (t == 0) {
        float used = 0.f;
        for (int i = 0; i < T; ++i) {
            usedL[i] = used;
            const int a = actL[i];
            used = (a == 0) ? 0.f : (used + demActL[i]);
        }
    }
    __syncthreads();

    // ---- per-thread row state ----
    const int cur = (t == 0) ? 0 : actL[t - 1];
    unsigned long long v0 = 0, v1 = 0, v2 = 0, v3 = 0;
    if (t > 0) {
        v0 = visW[0][t - 1] & ~1ull;   // depot bit always cleared
        v1 = visW[1][t - 1];
        v2 = visW[2][t - 1];
        v3 = visW[3][t - 1];
    }
    const float used = usedL[t];
    const float rem  = cap - used;
    const float capn = rem / cap;
    const bool  at_depot = (cur == 0);
    float4 pc;
    if (at_depot) { pc.x = 0.f; pc.y = 0.f; pc.z = 0.f; pc.w = 0.f; }
    else          { pc = psiL[cur]; }
    const float4 curC = zC[cur];
    const float ccx = curC.y, ccy = curC.z;
    const float tn = (float)t / 200.f;

    // ---- per-row query q[0..3] = Wq_b + Wq_w . ctx  (ctx is 8-dim) ----
    float q0, q1, q2, q3;
    {
        const float c0 = pc.x, c1 = pc.y, c2 = pc.z, c3 = pc.w;
        const float c4v = capn, c5 = tn, c6 = ccx, c7 = ccy;
        q0 = Wq_b[0] + Wq_w[0]*c0 + Wq_w[1]*c1 + Wq_w[2]*c2 + Wq_w[3]*c3
           + Wq_w[4]*c4v + Wq_w[5]*c5 + Wq_w[6]*c6 + Wq_w[7]*c7;
        q1 = Wq_b[1] + Wq_w[8]*c0 + Wq_w[9]*c1 + Wq_w[10]*c2 + Wq_w[11]*c3
           + Wq_w[12]*c4v + Wq_w[13]*c5 + Wq_w[14]*c6 + Wq_w[15]*c7;
        q2 = Wq_b[2] + Wq_w[16]*c0 + Wq_w[17]*c1 + Wq_w[18]*c2 + Wq_w[19]*c3
           + Wq_w[20]*c4v + Wq_w[21]*c5 + Wq_w[22]*c6 + Wq_w[23]*c7;
        q3 = Wq_b[3] + Wq_w[24]*c0 + Wq_w[25]*c1 + Wq_w[26]*c2 + Wq_w[27]*c3
           + Wq_w[28]*c4v + Wq_w[29]*c5 + Wq_w[30]*c6 + Wq_w[31]*c7;
    }

    // ---- 4 independent online-softmax streams over n ----
    float am0 = -1e30f, am1 = -1e30f, am2 = -1e30f, am3 = -1e30f;
    float as0 = 0.f, as1 = 0.f, as2 = 0.f, as3 = 0.f;
    float aw0 = 0.f, aw1 = 0.f, aw2 = 0.f, aw3 = 0.f;
    bool hasCust = false;

#define BODY(nn, ww, kk)                                                      \
    {                                                                         \
        const int n_ = (nn);                                                  \
        const float4 p4 = psiL[n_];                                           \
        const float4 c4 = zC[n_];                                             \
        float sco = q0 * p4.x + q1 * p4.y + q2 * p4.z + q3 * p4.w + c4.x;     \
        const float dx = c4.y - ccx, dy = c4.z - ccy;                         \
        sco -= mu * sqrtf(fmaf(dx, dx, fmaf(dy, dy, 1e-12f)));                \
        const bool visn = (((ww) >> (n_ & 63)) & 1);                          \
        const bool maskn = visn || (c4.w > rem);                              \
        hasCust = hasCust || !maskn;                                          \
        const float s_ = maskn ? -1e9f : sco;                                 \
        const float mN = fmaxf(am##kk, s_);                                   \
        const float al = __expf(am##kk - mN);                                 \
        const float d_ = __expf(s_ - mN);                                     \
        aw##kk = fmaf(as##kk, am##kk - mN, aw##kk) * al + d_ * (s_ - mN);     \
        as##kk = fmaf(as##kk, al, d_);                                        \
        am##kk = mN;                                                          \
    }

    BODY(1, v0, 1) BODY(2, v0, 2) BODY(3, v0, 3)
    for (int n = 4; n < 64; n += 4) {
        BODY(n + 0, v0, 0) BODY(n + 1, v0, 1) BODY(n + 2, v0, 2) BODY(n + 3, v0, 3)
    }
    for (int n = 64; n < 128; n += 4) {
        BODY(n + 0, v1, 0) BODY(n + 1, v1, 1) BODY(n + 2, v1, 2) BODY(n + 3, v1, 3)
    }
    for (int n = 128; n < 192; n += 4) {
        BODY(n + 0, v2, 0) BODY(n + 1, v2, 1) BODY(n + 2, v2, 2) BODY(n + 3, v2, 3)
    }
    BODY(192, v3, 0) BODY(193, v3, 1) BODY(194, v3, 2) BODY(195, v3, 3)
    BODY(196, v3, 0) BODY(197, v3, 1) BODY(198, v3, 2) BODY(199, v3, 3)
    BODY(200, v3, 0)

    // ---- depot (n = 0): mask = at_depot & hasCust; fold into stream 1 ----
    {
        const float4 p4 = psiL[0];
        const float4 c4 = zC[0];
        float sco = q0 * p4.x + q1 * p4.y + q2 * p4.z + q3 * p4.w + c4.x;
        const float dx = c4.y - ccx, dy = c4.z - ccy;
        sco -= mu * sqrtf(fmaf(dx, dx, fmaf(dy, dy, 1e-12f)));
        const float s_ = (at_depot && hasCust) ? -1e9f : sco;
        const float mN = fmaxf(am1, s_);
        const float al = __expf(am1 - mN);
        const float d_ = __expf(s_ - mN);
        aw1 = fmaf(as1, am1 - mN, aw1) * al + d_ * (s_ - mN);
        as1 = fmaf(as1, al, d_);
        am1 = mN;
    }

    // ---- merge the 4 streams ----
    const float M = fmaxf(fmaxf(am0, am1), fmaxf(am2, am3));
    const float e0 = __expf(am0 - M), e1 = __expf(am1 - M);
    const float e2 = __expf(am2 - M), e3 = __expf(am3 - M);
    const float S = as0 * e0 + as1 * e1 + as2 * e2 + as3 * e3;
    const float W = fmaf(as0, am0 - M, aw0) * e0 + fmaf(as1, am1 - M, aw1) * e1
                  + fmaf(as2, am2 - M, aw2) * e2 + fmaf(as3, am3 - M, aw3) * e3;

    // ---- sAct: recompute score at n = a_t ----
    float sAct;
    {
        const float4 p4 = psiL[a_t];
        const float4 c4 = zC[a_t];
        float sco = q0 * p4.x + q1 * p4.y + q2 * p4.z + q3 * p4.w + c4.x;
        const float dx = c4.y - ccx, dy = c4.z - ccy;
        sco -= mu * sqrtf(fmaf(dx, dx, fmaf(dy, dy, 1e-12f)));
        const unsigned long long wsel = (a_t < 64) ? v0 : (a_t < 128) ? v1
                                      : (a_t < 192) ? v2 : v3;
        const bool visn = ((wsel >> (a_t & 63)) & 1);
        bool maskn;
        if (a_t == 0) maskn = at_depot && hasCust;
        else          maskn = visn || (c4.w > rem);
        sAct = maskn ? -1e9f : sco;
    }

    const float L = logf(S);
    lp_out[b * T + t] = sAct - M - L;

    // ---- entropy: block reduction, one write per b ----
    float ent = L - W / S;
#pragma unroll
    for (int off = 32; off > 0; off >>= 1) ent += __shfl_xor(ent, off);
    if ((t & 63) == 0) entPart[t >> 6] = ent;
    __syncthreads();
    if (t == 0)
        ent_out[b] = (entPart[0] + entPart[1] + entPart[2] + entPart[3]) * (1.f / (float)T);
}

extern "C" void kernel_launch(void* const* d_in, const int* in_sizes, int n_in,
                              void* d_out, int out_size, void* d_ws, size_t ws_size,
                              hipStream_t stream) {
    const float* demands = (const float*)d_in[0];
    const float* coords  = (const float*)d_in[1];
    const float* psi     = (const float*)d_in[2];
    const float* Wq_w    = (const float*)d_in[3];
    const float* Wq_b    = (const float*)d_in[4];
    const float* lam_p   = (const float*)d_in[5];
    const float* mu_p    = (const float*)d_in[6];
    const float* nu_p    = (const float*)d_in[7];
    const int*   actions = (const int*)d_in[8];
    const int*   knn     = (const int*)d_in[9];
    const int*   cap_p   = (const int*)d_in[10];

    float* lp_out  = (float*)d_out;
    float* ent_out = lp_out + MB * T;

    fused_kernel<<<MB, T, 0, stream>>>(demands, coords, psi, Wq_w, Wq_b,
                                       lam_p, mu_p, nu_p, actions, knn, cap_p,
                                       lp_out, ent_out);
}

// Round 5
// 130.204 us; speedup vs baseline: 3.5962x; 1.0152x over previous
//
#include <hip/hip_runtime.h>
#include <hip/hip_bf16.h>
#include <math.h>

#define MB 512
#define T 256
#define NP1 201
#define KNN 5
#define RSW 12   // rowState words per row (48 B)

typedef unsigned long long u64;
typedef unsigned int u32;

// ---------------------------------------------------------------------------
// K1: per-batch t-sequential scans. One block per batch.
// rowState[row][12] = { rem, cur(int), a_t|depot<<31 (uint), pad,
//                       v0.lo, v0.hi, v1.lo, v1.hi, v2.lo, v2.hi, v3.lo, v3.hi }
// (vis = PRE-step visited mask, depot bit cleared). Also zeroes ent_out.
// ---------------------------------------------------------------------------
__global__ __launch_bounds__(256) void scan_kernel(
        const float* __restrict__ demands,
        const int* __restrict__ actions,
        const int* __restrict__ cap_p,
        float* __restrict__ rowState,
        float* __restrict__ ent_out) {
    __shared__ int   actL[T];
    __shared__ float demActL[T];
    __shared__ float usedL[T];
    __shared__ u64   visW[4][T];

    const int b = blockIdx.x;
    const int t = threadIdx.x;

    const int a_t = actions[b * T + t];
    actL[t] = a_t;
    demActL[t] = demands[b * NP1 + a_t];
    visW[0][t] = (a_t < 64)                ? (1ull << a_t)         : 0ull;
    visW[1][t] = (a_t >= 64 && a_t < 128)  ? (1ull << (a_t - 64))  : 0ull;
    visW[2][t] = (a_t >= 128 && a_t < 192) ? (1ull << (a_t - 128)) : 0ull;
    visW[3][t] = (a_t >= 192)              ? (1ull << (a_t - 192)) : 0ull;
    __syncthreads();

    // inclusive prefix-OR (bitwise => exact)
#pragma unroll
    for (int off = 1; off < T; off <<= 1) {
        u64 x0, x1, x2, x3;
        const bool doit = (t >= off);
        if (doit) { x0 = visW[0][t - off]; x1 = visW[1][t - off];
                    x2 = visW[2][t - off]; x3 = visW[3][t - off]; }
        __syncthreads();
        if (doit) { visW[0][t] |= x0; visW[1][t] |= x1;
                    visW[2][t] |= x2; visW[3][t] |= x3; }
        __syncthreads();
    }

    // serial f32 'used' scan (bit-exact sequential order)
    if (t == 0) {
        float used = 0.f;
        for (int i = 0; i < T; ++i) {
            usedL[i] = used;
            const int a = actL[i];
            used = (a == 0) ? 0.f : (used + demActL[i]);
        }
        ent_out[b] = 0.f;
    }
    __syncthreads();

    const float cap = fmaxf((float)cap_p[0], 1e-8f);
    const int cur = (t == 0) ? 0 : actL[t - 1];
    u64 v0 = 0, v1 = 0, v2 = 0, v3 = 0;
    if (t > 0) {
        v0 = visW[0][t - 1] & ~1ull;
        v1 = visW[1][t - 1];
        v2 = visW[2][t - 1];
        v3 = visW[3][t - 1];
    }
    const float rem = cap - usedL[t];
    const u32 meta = (u32)a_t | ((cur == 0) ? 0x80000000u : 0u);

    float* rs = rowState + (size_t)(b * T + t) * RSW;
    float4 w0 = {rem, __int_as_float(cur), __uint_as_float(meta), 0.f};
    ((float4*)rs)[0] = w0;
    uint4 wv0 = {(u32)v0, (u32)(v0 >> 32), (u32)v1, (u32)(v1 >> 32)};
    ((uint4*)rs)[1] = wv0;
    uint4 wv1 = {(u32)v2, (u32)(v2 >> 32), (u32)v3, (u32)(v3 >> 32)};
    ((uint4*)rs)[2] = wv1;
}

// ---------------------------------------------------------------------------
// K2: per-(b,n) t-invariant pack: { psi.x..w } { cst, x, y, dem }
// cst = lam*interference + nu*dem/cap
// ---------------------------------------------------------------------------
__global__ __launch_bounds__(256) void pack_kernel(
        const float* __restrict__ psi,
        const float* __restrict__ demands,
        const float* __restrict__ coords,
        const float* __restrict__ lam_p,
        const float* __restrict__ nu_p,
        const int* __restrict__ cap_p,
        const int* __restrict__ knn,
        float* __restrict__ pack) {
    const int i = blockIdx.x * blockDim.x + threadIdx.x;
    if (i >= MB * NP1) return;
    const int b = i / NP1;
    const float lam = fminf(fmaxf(lam_p[0], -2.f), 3.f);
    const float nu  = fminf(fmaxf(nu_p[0],  -2.f), 3.f);
    const float cap = fmaxf((float)cap_p[0], 1e-8f);

    const float4 pn = *(const float4*)(psi + (size_t)i * 4);
    float interf = 0.f;
    const int* kn = knn + (size_t)i * KNN;
#pragma unroll
    for (int k = 0; k < KNN; ++k) {
        const int j = kn[k];
        const float4 pj = *(const float4*)(psi + ((size_t)b * NP1 + j) * 4);
        interf += pn.x * pj.x + pn.y * pj.y + pn.z * pj.z + pn.w * pj.w;
    }
    const float dem = demands[i];
    const float2 cc2 = *(const float2*)(coords + (size_t)i * 2);
    const float cst = lam * interf + nu * (dem / cap);

    float* o = pack + (size_t)i * 8;
    ((float4*)o)[0] = pn;
    float4 oc = {cst, cc2.x, cc2.y, dem};
    ((float4*)o)[1] = oc;
}

// ---------------------------------------------------------------------------
// K3: hot loop. Block = 64 rows x 4 n-splits of one batch; grid = MB*4.
// No max-subtraction (scores bounded; masked -> e = 0 exactly).
// ---------------------------------------------------------------------------
__global__ __launch_bounds__(256, 8) void hot_kernel(
        const float* __restrict__ pack,
        const float* __restrict__ rowState,
        const float* __restrict__ Wq_w,
        const float* __restrict__ Wq_b,
        const float* __restrict__ mu_p,
        const int* __restrict__ cap_p,
        float* __restrict__ lp_out,
        float* __restrict__ ent_out) {
    __shared__ float4 psiL[NP1];
    __shared__ float4 zCL[NP1];
    __shared__ float  entPart[4];

    const int blk = blockIdx.x;
    const int b = blk >> 2, chunk = blk & 3;
    const int tid = threadIdx.x;
    const int rloc = tid >> 2, split = tid & 3;
    const int t = chunk * 64 + rloc;

    // stage pack for this batch (coalesced)
    const float4* pk = (const float4*)(pack + (size_t)b * NP1 * 8);
    for (int j = tid; j < 2 * NP1; j += 256) {
        const float4 v = pk[j];
        if (j & 1) zCL[j >> 1] = v; else psiL[j >> 1] = v;
    }
    __syncthreads();

    // row state
    const float4* rs = (const float4*)(rowState + (size_t)(b * T + t) * RSW);
    const float4 r0 = rs[0];
    const uint4 rv0 = ((const uint4*)rs)[1];
    const uint4 rv1 = ((const uint4*)rs)[2];
    const float rem = r0.x;
    const int cur = __float_as_int(r0.y);
    const u32 meta = __float_as_uint(r0.z);
    const int a_t = (int)(meta & 0xFFFFu);
    const bool at_depot = (meta >> 31) != 0;
    const u64 v0 = (u64)rv0.x | ((u64)rv0.y << 32);
    const u64 v1 = (u64)rv0.z | ((u64)rv0.w << 32);
    const u64 v2 = (u64)rv1.x | ((u64)rv1.y << 32);
    const u64 v3 = (u64)rv1.z | ((u64)rv1.w << 32);

    const float cap = fmaxf((float)cap_p[0], 1e-8f);
    const float mu  = fminf(fmaxf(mu_p[0], 0.f), 20.f);
    const float capn = rem / cap;
    const float tn = (float)t / 200.f;

    float4 pc = psiL[cur];
    if (at_depot) { pc.x = 0.f; pc.y = 0.f; pc.z = 0.f; pc.w = 0.f; }
    const float4 cz = zCL[cur];
    const float ccx = cz.y, ccy = cz.z;

    // per-row query q = Wq_b + Wq_w . ctx   (Wq reads are scalar/uniform)
    float q0, q1, q2, q3;
    {
        const float c0 = pc.x, c1 = pc.y, c2 = pc.z, c3 = pc.w;
        q0 = Wq_b[0] + Wq_w[0]*c0 + Wq_w[1]*c1 + Wq_w[2]*c2 + Wq_w[3]*c3
           + Wq_w[4]*capn + Wq_w[5]*tn + Wq_w[6]*ccx + Wq_w[7]*ccy;
        q1 = Wq_b[1] + Wq_w[8]*c0 + Wq_w[9]*c1 + Wq_w[10]*c2 + Wq_w[11]*c3
           + Wq_w[12]*capn + Wq_w[13]*tn + Wq_w[14]*ccx + Wq_w[15]*ccy;
        q2 = Wq_b[2] + Wq_w[16]*c0 + Wq_w[17]*c1 + Wq_w[18]*c2 + Wq_w[19]*c3
           + Wq_w[20]*capn + Wq_w[21]*tn + Wq_w[22]*ccx + Wq_w[23]*ccy;
        q3 = Wq_b[3] + Wq_w[24]*c0 + Wq_w[25]*c1 + Wq_w[26]*c2 + Wq_w[27]*c3
           + Wq_w[28]*capn + Wq_w[29]*tn + Wq_w[30]*ccx + Wq_w[31]*ccy;
    }

    // 50-bit vis window for this split (base in {1,51,101,151}, off != 0)
    const int base = 1 + split * 50;
    const int wsel = base >> 6;
    const u64 wlo = (wsel == 0) ? v0 : (wsel == 1) ? v1 : v2;
    const u64 whi = (wsel == 0) ? v1 : (wsel == 1) ? v2 : v3;
    const int off = base & 63;
    u64 window = (wlo >> off) | (whi << (64 - off));

    float S = 0.f, W = 0.f;
    bool hasC = false;
#pragma unroll 5
    for (int i = 0; i < 50; ++i) {
        const int n = base + i;
        const float4 p4 = psiL[n];
        const float4 c4 = zCL[n];
        float sco = fmaf(q0, p4.x, fmaf(q1, p4.y, fmaf(q2, p4.z, fmaf(q3, p4.w, c4.x))));
        const float dx = c4.y - ccx, dy = c4.z - ccy;
        sco = fmaf(-mu, sqrtf(fmaf(dx, dx, fmaf(dy, dy, 1e-12f))), sco);
        const bool maskn = ((u32)window & 1u) || (c4.w > rem);
        window >>= 1;
        hasC = hasC || !maskn;
        const float e = maskn ? 0.f : __expf(sco);
        S += e;
        W = fmaf(e, sco, W);
    }

    // combine hasCust across the 4 splits (adjacent lanes)
    int hc = hasC ? 1 : 0;
    hc |= __shfl_xor(hc, 1);
    hc |= __shfl_xor(hc, 2);
    const bool hasCust = hc != 0;

    // depot term (split 0 only): masked iff at_depot && hasCust
    if (split == 0) {
        const float4 p4 = psiL[0];
        const float4 c4 = zCL[0];
        float sco = fmaf(q0, p4.x, fmaf(q1, p4.y, fmaf(q2, p4.z, fmaf(q3, p4.w, c4.x))));
        const float dx = c4.y - ccx, dy = c4.z - ccy;
        sco = fmaf(-mu, sqrtf(fmaf(dx, dx, fmaf(dy, dy, 1e-12f))), sco);
        const bool mk = at_depot && hasCust;
        const float e = mk ? 0.f : __expf(sco);
        S += e;
        W = fmaf(e, sco, W);
    }

    // combine S, W across splits
    S += __shfl_xor(S, 1); S += __shfl_xor(S, 2);
    W += __shfl_xor(W, 1); W += __shfl_xor(W, 2);

    float entv = 0.f;
    if (split == 0) {
        const float L = logf(S);
        // sAct at n = a_t
        const float4 p4 = psiL[a_t];
        const float4 c4 = zCL[a_t];
        float sco = fmaf(q0, p4.x, fmaf(q1, p4.y, fmaf(q2, p4.z, fmaf(q3, p4.w, c4.x))));
        const float dx = c4.y - ccx, dy = c4.z - ccy;
        sco = fmaf(-mu, sqrtf(fmaf(dx, dx, fmaf(dy, dy, 1e-12f))), sco);
        bool maskA;
        if (a_t == 0) {
            maskA = at_depot && hasCust;
        } else {
            const u64 vw = (a_t < 64) ? v0 : (a_t < 128) ? v1 : (a_t < 192) ? v2 : v3;
            maskA = ((vw >> (a_t & 63)) & 1ull) || (c4.w > rem);
        }
        const float sAct = maskA ? -1e9f : sco;
        lp_out[b * T + t] = sAct - L;
        entv = L - W / S;
    }

    // entropy: wave reduce (non-split0 lanes contribute 0) -> block -> atomic
#pragma unroll
    for (int o = 32; o > 0; o >>= 1) entv += __shfl_xor(entv, o);
    if ((tid & 63) == 0) entPart[tid >> 6] = entv;
    __syncthreads();
    if (tid == 0)
        atomicAdd(&ent_out[b],
                  (entPart[0] + entPart[1] + entPart[2] + entPart[3]) * (1.f / (float)T));
}

extern "C" void kernel_launch(void* const* d_in, const int* in_sizes, int n_in,
                              void* d_out, int out_size, void* d_ws, size_t ws_size,
                              hipStream_t stream) {
    const float* demands = (const float*)d_in[0];
    const float* coords  = (const float*)d_in[1];
    const float* psi     = (const float*)d_in[2];
    const float* Wq_w    = (const float*)d_in[3];
    const float* Wq_b    = (const float*)d_in[4];
    const float* lam_p   = (const float*)d_in[5];
    const float* mu_p    = (const float*)d_in[6];
    const float* nu_p    = (const float*)d_in[7];
    const int*   actions = (const int*)d_in[8];
    const int*   knn     = (const int*)d_in[9];
    const int*   cap_p   = (const int*)d_in[10];

    float* lp_out  = (float*)d_out;
    float* ent_out = lp_out + MB * T;

    char* ws = (char*)d_ws;
    float* rowState = (float*)ws;                                   // 6,291,456 B
    float* pack     = (float*)(ws + (size_t)MB * T * RSW * 4);      // 3,293,184 B

    scan_kernel<<<MB, T, 0, stream>>>(demands, actions, cap_p, rowState, ent_out);
    pack_kernel<<<(MB * NP1 + 255) / 256, 256, 0, stream>>>(
        psi, demands, coords, lam_p, nu_p, cap_p, knn, pack);
    hot_kernel<<<MB * 4, 256, 0, stream>>>(
        pack, rowState, Wq_w, Wq_b, mu_p, cap_p, lp_out, ent_out);
}

// Round 6
// 118.117 us; speedup vs baseline: 3.9643x; 1.1023x over previous
//
#include <hip/hip_runtime.h>
#include <hip/hip_bf16.h>
#include <math.h>

#define MB 512
#define T 256
#define NP1 201
#define KNN 5
#define RSW 12   // rowState words per row (48 B)

typedef unsigned long long u64;
typedef unsigned int u32;

// ---------------------------------------------------------------------------
// K1: per-batch scans + per-node pack, one block per batch.
// rowState[row][12] = { rem, cur(int), a_t|depot<<31 (uint), pad,
//                       v0.lo, v0.hi, v1.lo, v1.hi, v2.lo, v2.hi, v3.lo, v3.hi }
// pack[(b*NP1+n)*8] = { psi.xyzw | cst, x, y, dem },  cst = lam*interf + nu*dem/cap
// 'used' is computed per-thread as the fold ((0+d_s)+...+d_{t-1}) in the exact
// sequential order (s = last depot visit before t, +1) -> bit-identical to the
// reference's serial f32 scan, but fully parallel.
// ---------------------------------------------------------------------------
__global__ __launch_bounds__(256) void scan_kernel(
        const float* __restrict__ demands,
        const float* __restrict__ coords,
        const float* __restrict__ psi,
        const int* __restrict__ actions,
        const int* __restrict__ knn,
        const float* __restrict__ lam_p,
        const float* __restrict__ nu_p,
        const int* __restrict__ cap_p,
        float* __restrict__ rowState,
        float* __restrict__ pack,
        float* __restrict__ ent_out) {
    __shared__ int   actL[T];
    __shared__ float demL[T];
    __shared__ int   lastDep[T];
    __shared__ u64   visW[4][T];

    const int b = blockIdx.x;
    const int t = threadIdx.x;

    const int a_t = actions[b * T + t];
    actL[t] = a_t;
    demL[t] = demands[b * NP1 + a_t];
    lastDep[t] = (a_t == 0) ? t : -1;
    visW[0][t] = (a_t < 64)                ? (1ull << a_t)         : 0ull;
    visW[1][t] = (a_t >= 64 && a_t < 128)  ? (1ull << (a_t - 64))  : 0ull;
    visW[2][t] = (a_t >= 128 && a_t < 192) ? (1ull << (a_t - 128)) : 0ull;
    visW[3][t] = (a_t >= 192)              ? (1ull << (a_t - 192)) : 0ull;

    // ---- pack part (t-invariant per node), n = t < 201; overlaps the scans ----
    float4 packP, packC;
    if (t < NP1) {
        const int n = t;
        const float lam = fminf(fmaxf(lam_p[0], -2.f), 3.f);
        const float nu  = fminf(fmaxf(nu_p[0],  -2.f), 3.f);
        const float capl = fmaxf((float)cap_p[0], 1e-8f);
        const float4 pn = *(const float4*)(psi + ((size_t)b * NP1 + n) * 4);
        const float2 cc2 = *(const float2*)(coords + ((size_t)b * NP1 + n) * 2);
        float interf = 0.f;
        const int* kn = knn + ((size_t)b * NP1 + n) * KNN;
#pragma unroll
        for (int k = 0; k < KNN; ++k) {
            const int j = kn[k];
            const float4 pj = *(const float4*)(psi + ((size_t)b * NP1 + j) * 4);
            interf += pn.x * pj.x + pn.y * pj.y + pn.z * pj.z + pn.w * pj.w;
        }
        const float dem = demands[b * NP1 + n];
        packP = pn;
        packC.x = lam * interf + nu * (dem / capl);
        packC.y = cc2.x; packC.z = cc2.y; packC.w = dem;
    }
    __syncthreads();

    // ---- fused prefix scans: OR (vis masks) + max (last depot index) ----
#pragma unroll
    for (int off = 1; off < T; off <<= 1) {
        u64 x0, x1, x2, x3; int xd;
        const bool doit = (t >= off);
        if (doit) { x0 = visW[0][t - off]; x1 = visW[1][t - off];
                    x2 = visW[2][t - off]; x3 = visW[3][t - off];
                    xd = lastDep[t - off]; }
        __syncthreads();
        if (doit) { visW[0][t] |= x0; visW[1][t] |= x1;
                    visW[2][t] |= x2; visW[3][t] |= x3;
                    lastDep[t] = max(lastDep[t], xd); }
        __syncthreads();
    }

    if (t == 0) ent_out[b] = 0.f;

    // ---- per-thread bit-exact 'used' fold over [s, t) ----
    const int s = (t == 0) ? 0 : (lastDep[t - 1] + 1);
    float used = 0.f;
    for (int j = s; j < t; ++j) used += demL[j];

    const float cap = fmaxf((float)cap_p[0], 1e-8f);
    const int cur = (t == 0) ? 0 : actL[t - 1];
    u64 v0 = 0, v1 = 0, v2 = 0, v3 = 0;
    if (t > 0) {
        v0 = visW[0][t - 1] & ~1ull;
        v1 = visW[1][t - 1];
        v2 = visW[2][t - 1];
        v3 = visW[3][t - 1];
    }
    const float rem = cap - used;
    const u32 meta = (u32)a_t | ((cur == 0) ? 0x80000000u : 0u);

    float* rs = rowState + (size_t)(b * T + t) * RSW;
    float4 w0 = {rem, __int_as_float(cur), __uint_as_float(meta), 0.f};
    ((float4*)rs)[0] = w0;
    uint4 wv0 = {(u32)v0, (u32)(v0 >> 32), (u32)v1, (u32)(v1 >> 32)};
    ((uint4*)rs)[1] = wv0;
    uint4 wv1 = {(u32)v2, (u32)(v2 >> 32), (u32)v3, (u32)(v3 >> 32)};
    ((uint4*)rs)[2] = wv1;

    if (t < NP1) {
        float* o = pack + ((size_t)b * NP1 + t) * 8;
        ((float4*)o)[0] = packP;
        ((float4*)o)[1] = packC;
    }
}

// ---------------------------------------------------------------------------
// K2: hot loop. Block = 64 rows x 4 n-splits of one batch; grid = MB*4.
// No max-subtraction (scores bounded; masked -> e = 0 exactly).
// ---------------------------------------------------------------------------
__global__ __launch_bounds__(256, 8) void hot_kernel(
        const float* __restrict__ pack,
        const float* __restrict__ rowState,
        const float* __restrict__ Wq_w,
        const float* __restrict__ Wq_b,
        const float* __restrict__ mu_p,
        const int* __restrict__ cap_p,
        float* __restrict__ lp_out,
        float* __restrict__ ent_out) {
    __shared__ float4 psiL[NP1];
    __shared__ float4 zCL[NP1];
    __shared__ float  entPart[4];

    const int blk = blockIdx.x;
    const int b = blk >> 2, chunk = blk & 3;
    const int tid = threadIdx.x;
    const int rloc = tid >> 2, split = tid & 3;
    const int t = chunk * 64 + rloc;

    // stage pack for this batch (coalesced)
    const float4* pk = (const float4*)(pack + (size_t)b * NP1 * 8);
    for (int j = tid; j < 2 * NP1; j += 256) {
        const float4 v = pk[j];
        if (j & 1) zCL[j >> 1] = v; else psiL[j >> 1] = v;
    }
    __syncthreads();

    // row state
    const float4* rs = (const float4*)(rowState + (size_t)(b * T + t) * RSW);
    const float4 r0 = rs[0];
    const uint4 rv0 = ((const uint4*)rs)[1];
    const uint4 rv1 = ((const uint4*)rs)[2];
    const float rem = r0.x;
    const int cur = __float_as_int(r0.y);
    const u32 meta = __float_as_uint(r0.z);
    const int a_t = (int)(meta & 0xFFFFu);
    const bool at_depot = (meta >> 31) != 0;
    const u64 v0 = (u64)rv0.x | ((u64)rv0.y << 32);
    const u64 v1 = (u64)rv0.z | ((u64)rv0.w << 32);
    const u64 v2 = (u64)rv1.x | ((u64)rv1.y << 32);
    const u64 v3 = (u64)rv1.z | ((u64)rv1.w << 32);

    const float cap = fmaxf((float)cap_p[0], 1e-8f);
    const float mu  = fminf(fmaxf(mu_p[0], 0.f), 20.f);
    const float capn = rem / cap;
    const float tn = (float)t / 200.f;

    float4 pc = psiL[cur];
    if (at_depot) { pc.x = 0.f; pc.y = 0.f; pc.z = 0.f; pc.w = 0.f; }
    const float4 cz = zCL[cur];
    const float ccx = cz.y, ccy = cz.z;

    // per-row query q = Wq_b + Wq_w . ctx   (Wq reads are scalar/uniform)
    float q0, q1, q2, q3;
    {
        const float c0 = pc.x, c1 = pc.y, c2 = pc.z, c3 = pc.w;
        q0 = Wq_b[0] + Wq_w[0]*c0 + Wq_w[1]*c1 + Wq_w[2]*c2 + Wq_w[3]*c3
           + Wq_w[4]*capn + Wq_w[5]*tn + Wq_w[6]*ccx + Wq_w[7]*ccy;
        q1 = Wq_b[1] + Wq_w[8]*c0 + Wq_w[9]*c1 + Wq_w[10]*c2 + Wq_w[11]*c3
           + Wq_w[12]*capn + Wq_w[13]*tn + Wq_w[14]*ccx + Wq_w[15]*ccy;
        q2 = Wq_b[2] + Wq_w[16]*c0 + Wq_w[17]*c1 + Wq_w[18]*c2 + Wq_w[19]*c3
           + Wq_w[20]*capn + Wq_w[21]*tn + Wq_w[22]*ccx + Wq_w[23]*ccy;
        q3 = Wq_b[3] + Wq_w[24]*c0 + Wq_w[25]*c1 + Wq_w[26]*c2 + Wq_w[27]*c3
           + Wq_w[28]*capn + Wq_w[29]*tn + Wq_w[30]*ccx + Wq_w[31]*ccy;
    }

    // 50-bit vis window for this split (base in {1,51,101,151})
    const int base = 1 + split * 50;
    const int wsel = base >> 6;
    const u64 wlo = (wsel == 0) ? v0 : (wsel == 1) ? v1 : v2;
    const u64 whi = (wsel == 0) ? v1 : (wsel == 1) ? v2 : v3;
    const int off = base & 63;
    u64 window = (wlo >> off) | (whi << (64 - off));

    float S = 0.f, W = 0.f;
    bool hasC = false;
#pragma unroll 5
    for (int i = 0; i < 50; ++i) {
        const int n = base + i;
        const float4 p4 = psiL[n];
        const float4 c4 = zCL[n];
        float sco = fmaf(q0, p4.x, fmaf(q1, p4.y, fmaf(q2, p4.z, fmaf(q3, p4.w, c4.x))));
        const float dx = c4.y - ccx, dy = c4.z - ccy;
        sco = fmaf(-mu, sqrtf(fmaf(dx, dx, fmaf(dy, dy, 1e-12f))), sco);
        const bool maskn = ((u32)window & 1u) || (c4.w > rem);
        window >>= 1;
        hasC = hasC || !maskn;
        const float e = maskn ? 0.f : __expf(sco);
        S += e;
        W = fmaf(e, sco, W);
    }

    // combine hasCust across the 4 splits (adjacent lanes)
    int hc = hasC ? 1 : 0;
    hc |= __shfl_xor(hc, 1);
    hc |= __shfl_xor(hc, 2);
    const bool hasCust = hc != 0;

    // depot term (split 0 only): masked iff at_depot && hasCust
    if (split == 0) {
        const float4 p4 = psiL[0];
        const float4 c4 = zCL[0];
        float sco = fmaf(q0, p4.x, fmaf(q1, p4.y, fmaf(q2, p4.z, fmaf(q3, p4.w, c4.x))));
        const float dx = c4.y - ccx, dy = c4.z - ccy;
        sco = fmaf(-mu, sqrtf(fmaf(dx, dx, fmaf(dy, dy, 1e-12f))), sco);
        const bool mk = at_depot && hasCust;
        const float e = mk ? 0.f : __expf(sco);
        S += e;
        W = fmaf(e, sco, W);
    }

    // combine S, W across splits
    S += __shfl_xor(S, 1); S += __shfl_xor(S, 2);
    W += __shfl_xor(W, 1); W += __shfl_xor(W, 2);

    float entv = 0.f;
    if (split == 0) {
        const float L = logf(S);
        // sAct at n = a_t
        const float4 p4 = psiL[a_t];
        const float4 c4 = zCL[a_t];
        float sco = fmaf(q0, p4.x, fmaf(q1, p4.y, fmaf(q2, p4.z, fmaf(q3, p4.w, c4.x))));
        const float dx = c4.y - ccx, dy = c4.z - ccy;
        sco = fmaf(-mu, sqrtf(fmaf(dx, dx, fmaf(dy, dy, 1e-12f))), sco);
        bool maskA;
        if (a_t == 0) {
            maskA = at_depot && hasCust;
        } else {
            const u64 vw = (a_t < 64) ? v0 : (a_t < 128) ? v1 : (a_t < 192) ? v2 : v3;
            maskA = ((vw >> (a_t & 63)) & 1ull) || (c4.w > rem);
        }
        const float sAct = maskA ? -1e9f : sco;
        lp_out[b * T + t] = sAct - L;
        entv = L - W / S;
    }

    // entropy: wave reduce (non-split0 lanes contribute 0) -> block -> atomic
#pragma unroll
    for (int o = 32; o > 0; o >>= 1) entv += __shfl_xor(entv, o);
    if ((tid & 63) == 0) entPart[tid >> 6] = entv;
    __syncthreads();
    if (tid == 0)
        atomicAdd(&ent_out[b],
                  (entPart[0] + entPart[1] + entPart[2] + entPart[3]) * (1.f / (float)T));
}

extern "C" void kernel_launch(void* const* d_in, const int* in_sizes, int n_in,
                              void* d_out, int out_size, void* d_ws, size_t ws_size,
                              hipStream_t stream) {
    const float* demands = (const float*)d_in[0];
    const float* coords  = (const float*)d_in[1];
    const float* psi     = (const float*)d_in[2];
    const float* Wq_w    = (const float*)d_in[3];
    const float* Wq_b    = (const float*)d_in[4];
    const float* lam_p   = (const float*)d_in[5];
    const float* mu_p    = (const float*)d_in[6];
    const float* nu_p    = (const float*)d_in[7];
    const int*   actions = (const int*)d_in[8];
    const int*   knn     = (const int*)d_in[9];
    const int*   cap_p   = (const int*)d_in[10];

    float* lp_out  = (float*)d_out;
    float* ent_out = lp_out + MB * T;

    char* ws = (char*)d_ws;
    float* rowState = (float*)ws;                                   // 6,291,456 B
    float* pack     = (float*)(ws + (size_t)MB * T * RSW * 4);      // 3,293,184 B

    scan_kernel<<<MB, T, 0, stream>>>(demands, coords, psi, actions, knn,
                                      lam_p, nu_p, cap_p, rowState, pack, ent_out);
    hot_kernel<<<MB * 4, 256, 0, stream>>>(
        pack, rowState, Wq_w, Wq_b, mu_p, cap_p, lp_out, ent_out);
}

// Round 7
// 108.198 us; speedup vs baseline: 4.3277x; 1.0917x over previous
//
#include <hip/hip_runtime.h>
#include <hip/hip_bf16.h>
#include <math.h>

#define MB 512
#define T 256
#define NP1 201
#define KNN 5

typedef unsigned long long u64;
typedef unsigned int u32;

// ---------------------------------------------------------------------------
// Fused kernel. Grid = MB*4 blocks of 256 threads; block = (batch b, chunk).
// Phase A (thread = t in [0,256)): redundant per-batch scan, all in LDS/regs:
//   - visited-mask inclusive prefix-OR via register shfl_up (bitwise => exact)
//   - last-depot prefix-max the same way
//   - bit-exact f32 'used' fold over [s,t) in reference order (LDS broadcast)
//   - per-node pack (psi | cst,x,y,dem) for n = t < 201
// Phase B (thread = 64 rows x 4 n-splits): scores + softmax-sum + entropy.
// ---------------------------------------------------------------------------
__global__ __launch_bounds__(256, 8) void fused_kernel(
        const float* __restrict__ demands,
        const float* __restrict__ coords,
        const float* __restrict__ psi,
        const float* __restrict__ Wq_w,
        const float* __restrict__ Wq_b,
        const float* __restrict__ lam_p,
        const float* __restrict__ mu_p,
        const float* __restrict__ nu_p,
        const int* __restrict__ actions,
        const int* __restrict__ knn,
        const int* __restrict__ cap_p,
        float* __restrict__ lp_out,
        float* __restrict__ entPartial) {
    __shared__ float4 psiL[NP1];
    __shared__ float4 zCL[NP1];
    __shared__ u64   visW[4][T];   // final inclusive prefix-OR
    __shared__ float remL[T];
    __shared__ int   actL[T];
    __shared__ float demL[T];
    __shared__ u64   aggV[4][4];
    __shared__ int   aggD[4];
    __shared__ float entPart[4];

    const int blk = blockIdx.x;
    const int b = blk >> 2, chunk = blk & 3;
    const int tid = threadIdx.x;
    const int lane = tid & 63, wv = tid >> 6;

    const float cap = fmaxf((float)cap_p[0], 1e-8f);

    // ================= Phase A: per-batch scan (thread = t) =================
    const int t = tid;
    const int a_t = actions[b * T + t];
    actL[t] = a_t;
    demL[t] = demands[b * NP1 + a_t];

    u64 m0 = (a_t < 64)                ? (1ull << a_t)         : 0ull;
    u64 m1 = (a_t >= 64 && a_t < 128)  ? (1ull << (a_t - 64))  : 0ull;
    u64 m2 = (a_t >= 128 && a_t < 192) ? (1ull << (a_t - 128)) : 0ull;
    u64 m3 = (a_t >= 192)              ? (1ull << (a_t - 192)) : 0ull;
    int d = (a_t == 0) ? t : -1;

    // pack (t-invariant per node), n = t < 201 — loads overlap the scan
    float4 packP, packC;
    if (t < NP1) {
        const float lam = fminf(fmaxf(lam_p[0], -2.f), 3.f);
        const float nu  = fminf(fmaxf(nu_p[0],  -2.f), 3.f);
        const float4 pn = *(const float4*)(psi + ((size_t)b * NP1 + t) * 4);
        const float2 cc2 = *(const float2*)(coords + ((size_t)b * NP1 + t) * 2);
        float interf = 0.f;
        const int* kn = knn + ((size_t)b * NP1 + t) * KNN;
#pragma unroll
        for (int k = 0; k < KNN; ++k) {
            const int j = kn[k];
            const float4 pj = *(const float4*)(psi + ((size_t)b * NP1 + j) * 4);
            interf += pn.x * pj.x + pn.y * pj.y + pn.z * pj.z + pn.w * pj.w;
        }
        const float dem = demands[b * NP1 + t];
        packP = pn;
        packC.x = lam * interf + nu * (dem / cap);
        packC.y = cc2.x; packC.z = cc2.y; packC.w = dem;
    }

    // wave-level inclusive scans via shfl_up (lane<off returns own: no-op)
#pragma unroll
    for (int off = 1; off < 64; off <<= 1) {
        m0 |= __shfl_up(m0, off);
        m1 |= __shfl_up(m1, off);
        m2 |= __shfl_up(m2, off);
        m3 |= __shfl_up(m3, off);
        d = max(d, __shfl_up(d, off));
    }
    if (lane == 63) {
        aggV[0][wv] = m0; aggV[1][wv] = m1;
        aggV[2][wv] = m2; aggV[3][wv] = m3;
        aggD[wv] = d;
    }
    __syncthreads();   // barrier 1

    // fold in aggregates of lower waves
    u64 p0 = 0, p1 = 0, p2 = 0, p3 = 0; int pd = -1;
    for (int u = 0; u < wv; ++u) {
        p0 |= aggV[0][u]; p1 |= aggV[1][u];
        p2 |= aggV[2][u]; p3 |= aggV[3][u];
        pd = max(pd, aggD[u]);
    }
    m0 |= p0; m1 |= p1; m2 |= p2; m3 |= p3; d = max(d, pd);
    visW[0][t] = m0; visW[1][t] = m1; visW[2][t] = m2; visW[3][t] = m3;

    // s = (last depot index <= t-1) + 1 ;  d_{t-1} via shfl (lane0: lower aggs)
    int dPrev = __shfl_up(d, 1);
    if (lane == 0) dPrev = pd;
    const int s = dPrev + 1;     // t==0 -> pd=-1 -> s=0

    // bit-exact sequential f32 fold over [s, t) — segment-uniform broadcast
    float used = 0.f;
    for (int j = s; j < t; ++j) used += demL[j];
    remL[t] = cap - used;

    if (t < NP1) { psiL[t] = packP; zCL[t] = packC; }
    __syncthreads();   // barrier 2

    // ============ Phase B: hot loop (thread = 64 rows x 4 splits) ===========
    const int rloc = tid >> 2, split = tid & 3;
    const int tr = chunk * 64 + rloc;

    const float rem = remL[tr];
    const int a_row = actL[tr];
    const int cur = (tr == 0) ? 0 : actL[tr - 1];
    const bool at_depot = (cur == 0);
    u64 v0 = 0, v1 = 0, v2 = 0, v3 = 0;
    if (tr > 0) {
        v0 = visW[0][tr - 1] & ~1ull;   // depot bit always cleared
        v1 = visW[1][tr - 1];
        v2 = visW[2][tr - 1];
        v3 = visW[3][tr - 1];
    }

    const float mu  = fminf(fmaxf(mu_p[0], 0.f), 20.f);
    const float capn = rem / cap;
    const float tn = (float)tr / 200.f;

    float4 pc = psiL[cur];
    if (at_depot) { pc.x = 0.f; pc.y = 0.f; pc.z = 0.f; pc.w = 0.f; }
    const float4 cz = zCL[cur];
    const float ccx = cz.y, ccy = cz.z;

    // per-row query q = Wq_b + Wq_w . ctx (Wq reads scalar/uniform)
    float q0, q1, q2, q3;
    {
        const float c0 = pc.x, c1 = pc.y, c2 = pc.z, c3 = pc.w;
        q0 = Wq_b[0] + Wq_w[0]*c0 + Wq_w[1]*c1 + Wq_w[2]*c2 + Wq_w[3]*c3
           + Wq_w[4]*capn + Wq_w[5]*tn + Wq_w[6]*ccx + Wq_w[7]*ccy;
        q1 = Wq_b[1] + Wq_w[8]*c0 + Wq_w[9]*c1 + Wq_w[10]*c2 + Wq_w[11]*c3
           + Wq_w[12]*capn + Wq_w[13]*tn + Wq_w[14]*ccx + Wq_w[15]*ccy;
        q2 = Wq_b[2] + Wq_w[16]*c0 + Wq_w[17]*c1 + Wq_w[18]*c2 + Wq_w[19]*c3
           + Wq_w[20]*capn + Wq_w[21]*tn + Wq_w[22]*ccx + Wq_w[23]*ccy;
        q3 = Wq_b[3] + Wq_w[24]*c0 + Wq_w[25]*c1 + Wq_w[26]*c2 + Wq_w[27]*c3
           + Wq_w[28]*capn + Wq_w[29]*tn + Wq_w[30]*ccx + Wq_w[31]*ccy;
    }

    // 50-bit vis window for this split (base in {1,51,101,151})
    const int base = 1 + split * 50;
    const int wsel = base >> 6;
    const u64 wlo = (wsel == 0) ? v0 : (wsel == 1) ? v1 : v2;
    const u64 whi = (wsel == 0) ? v1 : (wsel == 1) ? v2 : v3;
    const int off = base & 63;
    u64 window = (wlo >> off) | (whi << (64 - off));

    float S = 0.f, W = 0.f;
    bool hasC = false;
#pragma unroll 5
    for (int i = 0; i < 50; ++i) {
        const int n = base + i;
        const float4 p4 = psiL[n];
        const float4 c4 = zCL[n];
        float sco = fmaf(q0, p4.x, fmaf(q1, p4.y, fmaf(q2, p4.z, fmaf(q3, p4.w, c4.x))));
        const float dx = c4.y - ccx, dy = c4.z - ccy;
        sco = fmaf(-mu, __builtin_amdgcn_sqrtf(fmaf(dx, dx, fmaf(dy, dy, 1e-12f))), sco);
        const bool maskn = ((u32)window & 1u) || (c4.w > rem);
        window >>= 1;
        hasC = hasC || !maskn;
        const float e = maskn ? 0.f : __expf(sco);
        S += e;
        W = fmaf(e, sco, W);
    }

    // hasCust across the 4 splits (adjacent lanes)
    int hc = hasC ? 1 : 0;
    hc |= __shfl_xor(hc, 1);
    hc |= __shfl_xor(hc, 2);
    const bool hasCust = hc != 0;

    // depot term (split 0 only)
    if (split == 0) {
        const float4 p4 = psiL[0];
        const float4 c4 = zCL[0];
        float sco = fmaf(q0, p4.x, fmaf(q1, p4.y, fmaf(q2, p4.z, fmaf(q3, p4.w, c4.x))));
        const float dx = c4.y - ccx, dy = c4.z - ccy;
        sco = fmaf(-mu, __builtin_amdgcn_sqrtf(fmaf(dx, dx, fmaf(dy, dy, 1e-12f))), sco);
        const bool mk = at_depot && hasCust;
        const float e = mk ? 0.f : __expf(sco);
        S += e;
        W = fmaf(e, sco, W);
    }

    // combine S, W across splits
    S += __shfl_xor(S, 1); S += __shfl_xor(S, 2);
    W += __shfl_xor(W, 1); W += __shfl_xor(W, 2);

    float entv = 0.f;
    if (split == 0) {
        const float L = __logf(S);
        const float4 p4 = psiL[a_row];
        const float4 c4 = zCL[a_row];
        float sco = fmaf(q0, p4.x, fmaf(q1, p4.y, fmaf(q2, p4.z, fmaf(q3, p4.w, c4.x))));
        const float dx = c4.y - ccx, dy = c4.z - ccy;
        sco = fmaf(-mu, __builtin_amdgcn_sqrtf(fmaf(dx, dx, fmaf(dy, dy, 1e-12f))), sco);
        bool maskA;
        if (a_row == 0) {
            maskA = at_depot && hasCust;
        } else {
            const u64 vw = (a_row < 64) ? v0 : (a_row < 128) ? v1
                         : (a_row < 192) ? v2 : v3;
            maskA = ((vw >> (a_row & 63)) & 1ull) || (c4.w > rem);
        }
        const float sAct = maskA ? -1e9f : sco;
        lp_out[b * T + tr] = sAct - L;
        entv = L - W / S;
    }

    // entropy partial: wave reduce -> block -> one global write per block
#pragma unroll
    for (int o = 32; o > 0; o >>= 1) entv += __shfl_xor(entv, o);
    if (lane == 0) entPart[wv] = entv;
    __syncthreads();   // barrier 3
    if (tid == 0)
        entPartial[b * 4 + chunk] = entPart[0] + entPart[1] + entPart[2] + entPart[3];
}

// ---------------------------------------------------------------------------
// Tiny: ent_out[b] = mean over t of per-row entropy = sum(partials)/T
// ---------------------------------------------------------------------------
__global__ __launch_bounds__(256) void ent_sum_kernel(
        const float* __restrict__ entPartial, float* __restrict__ ent_out) {
    const int b = blockIdx.x * blockDim.x + threadIdx.x;
    if (b < MB) {
        const float* p = entPartial + b * 4;
        ent_out[b] = (p[0] + p[1] + p[2] + p[3]) * (1.f / (float)T);
    }
}

extern "C" void kernel_launch(void* const* d_in, const int* in_sizes, int n_in,
                              void* d_out, int out_size, void* d_ws, size_t ws_size,
                              hipStream_t stream) {
    const float* demands = (const float*)d_in[0];
    const float* coords  = (const float*)d_in[1];
    const float* psi     = (const float*)d_in[2];
    const float* Wq_w    = (const float*)d_in[3];
    const float* Wq_b    = (const float*)d_in[4];
    const float* lam_p   = (const float*)d_in[5];
    const float* mu_p    = (const float*)d_in[6];
    const float* nu_p    = (const float*)d_in[7];
    const int*   actions = (const int*)d_in[8];
    const int*   knn     = (const int*)d_in[9];
    const int*   cap_p   = (const int*)d_in[10];

    float* lp_out  = (float*)d_out;
    float* ent_out = lp_out + MB * T;

    float* entPartial = (float*)d_ws;   // MB*4 floats = 8 KB

    fused_kernel<<<MB * 4, 256, 0, stream>>>(
        demands, coords, psi, Wq_w, Wq_b, lam_p, mu_p, nu_p,
        actions, knn, cap_p, lp_out, entPartial);
    ent_sum_kernel<<<2, 256, 0, stream>>>(entPartial, ent_out);
}

// Round 8
// 107.572 us; speedup vs baseline: 4.3529x; 1.0058x over previous
//
#include <hip/hip_runtime.h>
#include <hip/hip_bf16.h>
#include <math.h>

#define MB 512
#define T 256
#define NP1 201
#define KNN 5

typedef unsigned long long u64;
typedef unsigned int u32;

// ---------------------------------------------------------------------------
// Fused kernel. Grid = MB*4 blocks of 256 threads; block = (batch b, chunk).
// Phase A (thread = t): redundant per-batch scan in LDS/registers:
//   - visited-mask inclusive prefix-OR via register shfl_up (bitwise => exact)
//   - last-depot prefix-max the same way
//   - bit-exact f32 'used' fold over [s,t) in reference order (LDS broadcast)
//   - per-node pack (psi | cst,x,y,dem) for n = t < 201
// Phase B (thread = 64 rows x 4 n-splits): scores + softmax-sum + entropy.
// hasCust is derived from S>0 (unmasked e=exp(sco)>0 strictly; masked adds 0).
// ---------------------------------------------------------------------------
__global__ __launch_bounds__(256, 8) void fused_kernel(
        const float* __restrict__ demands,
        const float* __restrict__ coords,
        const float* __restrict__ psi,
        const float* __restrict__ Wq_w,
        const float* __restrict__ Wq_b,
        const float* __restrict__ lam_p,
        const float* __restrict__ mu_p,
        const float* __restrict__ nu_p,
        const int* __restrict__ actions,
        const int* __restrict__ knn,
        const int* __restrict__ cap_p,
        float* __restrict__ lp_out,
        float* __restrict__ entPartial) {
    __shared__ float4 psiL[NP1];
    __shared__ float4 zCL[NP1];
    __shared__ u64   visW[4][T];   // final inclusive prefix-OR
    __shared__ float remL[T];
    __shared__ int   actL[T];
    __shared__ float demL[T];
    __shared__ u64   aggV[4][4];
    __shared__ int   aggD[4];
    __shared__ float entPart[4];

    const int blk = blockIdx.x;
    const int b = blk >> 2, chunk = blk & 3;
    const int tid = threadIdx.x;
    const int lane = tid & 63, wv = tid >> 6;

    const float cap = fmaxf((float)cap_p[0], 1e-8f);

    // ================= Phase A: per-batch scan (thread = t) =================
    const int t = tid;
    const int a_t = actions[b * T + t];
    actL[t] = a_t;
    demL[t] = demands[b * NP1 + a_t];

    u64 m0 = (a_t < 64)                ? (1ull << a_t)         : 0ull;
    u64 m1 = (a_t >= 64 && a_t < 128)  ? (1ull << (a_t - 64))  : 0ull;
    u64 m2 = (a_t >= 128 && a_t < 192) ? (1ull << (a_t - 128)) : 0ull;
    u64 m3 = (a_t >= 192)              ? (1ull << (a_t - 192)) : 0ull;
    int d = (a_t == 0) ? t : -1;

    // pack (t-invariant per node), n = t < 201 — loads overlap the scan
    float4 packP, packC;
    if (t < NP1) {
        const float lam = fminf(fmaxf(lam_p[0], -2.f), 3.f);
        const float nu  = fminf(fmaxf(nu_p[0],  -2.f), 3.f);
        const float4 pn = *(const float4*)(psi + ((size_t)b * NP1 + t) * 4);
        const float2 cc2 = *(const float2*)(coords + ((size_t)b * NP1 + t) * 2);
        float interf = 0.f;
        const int* kn = knn + ((size_t)b * NP1 + t) * KNN;
#pragma unroll
        for (int k = 0; k < KNN; ++k) {
            const int j = kn[k];
            const float4 pj = *(const float4*)(psi + ((size_t)b * NP1 + j) * 4);
            interf += pn.x * pj.x + pn.y * pj.y + pn.z * pj.z + pn.w * pj.w;
        }
        const float dem = demands[b * NP1 + t];
        packP = pn;
        packC.x = lam * interf + nu * (dem / cap);
        packC.y = cc2.x; packC.z = cc2.y; packC.w = dem;
    }

    // wave-level inclusive scans via shfl_up (lane<off returns own: no-op)
#pragma unroll
    for (int off = 1; off < 64; off <<= 1) {
        m0 |= __shfl_up(m0, off);
        m1 |= __shfl_up(m1, off);
        m2 |= __shfl_up(m2, off);
        m3 |= __shfl_up(m3, off);
        d = max(d, __shfl_up(d, off));
    }
    if (lane == 63) {
        aggV[0][wv] = m0; aggV[1][wv] = m1;
        aggV[2][wv] = m2; aggV[3][wv] = m3;
        aggD[wv] = d;
    }
    __syncthreads();   // barrier 1

    // fold in aggregates of lower waves
    u64 p0 = 0, p1 = 0, p2 = 0, p3 = 0; int pd = -1;
    for (int u = 0; u < wv; ++u) {
        p0 |= aggV[0][u]; p1 |= aggV[1][u];
        p2 |= aggV[2][u]; p3 |= aggV[3][u];
        pd = max(pd, aggD[u]);
    }
    m0 |= p0; m1 |= p1; m2 |= p2; m3 |= p3; d = max(d, pd);
    visW[0][t] = m0; visW[1][t] = m1; visW[2][t] = m2; visW[3][t] = m3;

    // s = (last depot index <= t-1) + 1 ;  d_{t-1} via shfl (lane0: lower aggs)
    int dPrev = __shfl_up(d, 1);
    if (lane == 0) dPrev = pd;
    const int s = dPrev + 1;     // t==0 -> pd=-1 -> s=0

    // bit-exact sequential f32 fold over [s, t) — segment-uniform broadcast
    float used = 0.f;
    for (int j = s; j < t; ++j) used += demL[j];
    remL[t] = cap - used;

    if (t < NP1) { psiL[t] = packP; zCL[t] = packC; }
    __syncthreads();   // barrier 2

    // ============ Phase B: hot loop (thread = 64 rows x 4 splits) ===========
    const int rloc = tid >> 2, split = tid & 3;
    const int tr = chunk * 64 + rloc;

    const float rem = remL[tr];
    const int a_row = actL[tr];
    const int cur = (tr == 0) ? 0 : actL[tr - 1];
    const bool at_depot = (cur == 0);
    u64 v0 = 0, v1 = 0, v2 = 0, v3 = 0;
    if (tr > 0) {
        v0 = visW[0][tr - 1] & ~1ull;   // depot bit always cleared
        v1 = visW[1][tr - 1];
        v2 = visW[2][tr - 1];
        v3 = visW[3][tr - 1];
    }

    const float mu  = fminf(fmaxf(mu_p[0], 0.f), 20.f);
    const float capn = rem / cap;
    const float tn = (float)tr / 200.f;

    float4 pc = psiL[cur];
    if (at_depot) { pc.x = 0.f; pc.y = 0.f; pc.z = 0.f; pc.w = 0.f; }
    const float4 cz = zCL[cur];
    const float ccx = cz.y, ccy = cz.z;

    // per-row query q = Wq_b + Wq_w . ctx (Wq reads scalar/uniform)
    float q0, q1, q2, q3;
    {
        const float c0 = pc.x, c1 = pc.y, c2 = pc.z, c3 = pc.w;
        q0 = Wq_b[0] + Wq_w[0]*c0 + Wq_w[1]*c1 + Wq_w[2]*c2 + Wq_w[3]*c3
           + Wq_w[4]*capn + Wq_w[5]*tn + Wq_w[6]*ccx + Wq_w[7]*ccy;
        q1 = Wq_b[1] + Wq_w[8]*c0 + Wq_w[9]*c1 + Wq_w[10]*c2 + Wq_w[11]*c3
           + Wq_w[12]*capn + Wq_w[13]*tn + Wq_w[14]*ccx + Wq_w[15]*ccy;
        q2 = Wq_b[2] + Wq_w[16]*c0 + Wq_w[17]*c1 + Wq_w[18]*c2 + Wq_w[19]*c3
           + Wq_w[20]*capn + Wq_w[21]*tn + Wq_w[22]*ccx + Wq_w[23]*ccy;
        q3 = Wq_b[3] + Wq_w[24]*c0 + Wq_w[25]*c1 + Wq_w[26]*c2 + Wq_w[27]*c3
           + Wq_w[28]*capn + Wq_w[29]*tn + Wq_w[30]*ccx + Wq_w[31]*ccy;
    }

    // 50-bit vis window for this split (base in {1,51,101,151})
    const int base = 1 + split * 50;
    const int wsel = base >> 6;
    const u64 wlo = (wsel == 0) ? v0 : (wsel == 1) ? v1 : v2;
    const u64 whi = (wsel == 0) ? v1 : (wsel == 1) ? v2 : v3;
    const int off = base & 63;
    u64 window = (wlo >> off) | (whi << (64 - off));

    float S = 0.f, W = 0.f;
#pragma unroll 10
    for (int i = 0; i < 50; ++i) {
        const int n = base + i;
        const float4 p4 = psiL[n];
        const float4 c4 = zCL[n];
        float sco = fmaf(q0, p4.x, fmaf(q1, p4.y, fmaf(q2, p4.z, fmaf(q3, p4.w, c4.x))));
        const float dx = c4.y - ccx, dy = c4.z - ccy;
        sco = fmaf(-mu, __builtin_amdgcn_sqrtf(fmaf(dx, dx, fmaf(dy, dy, 1e-12f))), sco);
        const bool maskn = (((u32)(window >> i)) & 1u) || (c4.w > rem);
        const float e = maskn ? 0.f : __expf(sco);
        S += e;
        W = fmaf(e, sco, W);
    }

    // combine S, W across the 4 splits (customers only)
    S += __shfl_xor(S, 1); S += __shfl_xor(S, 2);
    W += __shfl_xor(W, 1); W += __shfl_xor(W, 2);

    // hasCust == any customer unmasked == S > 0 (e > 0 strictly when unmasked)
    const bool hasCust = S > 0.f;

    float entv = 0.f;
    if (split == 0) {
        // depot term (n = 0): masked iff at_depot && hasCust
        {
            const float4 p4 = psiL[0];
            const float4 c4 = zCL[0];
            float sco = fmaf(q0, p4.x, fmaf(q1, p4.y, fmaf(q2, p4.z, fmaf(q3, p4.w, c4.x))));
            const float dx = c4.y - ccx, dy = c4.z - ccy;
            sco = fmaf(-mu, __builtin_amdgcn_sqrtf(fmaf(dx, dx, fmaf(dy, dy, 1e-12f))), sco);
            const bool mk = at_depot && hasCust;
            const float e = mk ? 0.f : __expf(sco);
            S += e;
            W = fmaf(e, sco, W);
        }
        const float L = __logf(S);
        const float4 p4 = psiL[a_row];
        const float4 c4 = zCL[a_row];
        float sco = fmaf(q0, p4.x, fmaf(q1, p4.y, fmaf(q2, p4.z, fmaf(q3, p4.w, c4.x))));
        const float dx = c4.y - ccx, dy = c4.z - ccy;
        sco = fmaf(-mu, __builtin_amdgcn_sqrtf(fmaf(dx, dx, fmaf(dy, dy, 1e-12f))), sco);
        bool maskA;
        if (a_row == 0) {
            maskA = at_depot && hasCust;
        } else {
            const u64 vw = (a_row < 64) ? v0 : (a_row < 128) ? v1
                         : (a_row < 192) ? v2 : v3;
            maskA = ((vw >> (a_row & 63)) & 1ull) || (c4.w > rem);
        }
        const float sAct = maskA ? -1e9f : sco;
        lp_out[b * T + tr] = sAct - L;
        entv = L - W / S;
    }

    // entropy partial: wave reduce -> block -> one global write per block
#pragma unroll
    for (int o = 32; o > 0; o >>= 1) entv += __shfl_xor(entv, o);
    if (lane == 0) entPart[wv] = entv;
    __syncthreads();   // barrier 3
    if (tid == 0)
        entPartial[b * 4 + chunk] = entPart[0] + entPart[1] + entPart[2] + entPart[3];
}

// ---------------------------------------------------------------------------
// Tiny: ent_out[b] = mean over t of per-row entropy = sum(partials)/T
// ---------------------------------------------------------------------------
__global__ __launch_bounds__(512) void ent_sum_kernel(
        const float* __restrict__ entPartial, float* __restrict__ ent_out) {
    const int b = threadIdx.x;
    if (b < MB) {
        const float4 p = ((const float4*)entPartial)[b];
        ent_out[b] = (p.x + p.y + p.z + p.w) * (1.f / (float)T);
    }
}

extern "C" void kernel_launch(void* const* d_in, const int* in_sizes, int n_in,
                              void* d_out, int out_size, void* d_ws, size_t ws_size,
                              hipStream_t stream) {
    const float* demands = (const float*)d_in[0];
    const float* coords  = (const float*)d_in[1];
    const float* psi     = (const float*)d_in[2];
    const float* Wq_w    = (const float*)d_in[3];
    const float* Wq_b    = (const float*)d_in[4];
    const float* lam_p   = (const float*)d_in[5];
    const float* mu_p    = (const float*)d_in[6];
    const float* nu_p    = (const float*)d_in[7];
    const int*   actions = (const int*)d_in[8];
    const int*   knn     = (const int*)d_in[9];
    const int*   cap_p   = (const int*)d_in[10];

    float* lp_out  = (float*)d_out;
    float* ent_out = lp_out + MB * T;

    float* entPartial = (float*)d_ws;   // MB*4 floats = 8 KB

    fused_kernel<<<MB * 4, 256, 0, stream>>>(
        demands, coords, psi, Wq_w, Wq_b, lam_p, mu_p, nu_p,
        actions, knn, cap_p, lp_out, entPartial);
    ent_sum_kernel<<<1, 512, 0, stream>>>(entPartial, ent_out);
}